// Round 9
// baseline (55.585 us; speedup 1.0000x reference)
//
#include <hip/hip_runtime.h>

#define BATCH   16384
#define NKNOW   128
#define NEDGE   253
#define RPB     16

typedef __attribute__((ext_vector_type(8))) short  s16x8;   // 8 bf16 MFMA operand
typedef __attribute__((ext_vector_type(4))) float  f32x4;   // MFMA accumulator
typedef __attribute__((ext_vector_type(4))) int    i32x4;

typedef unsigned short u16;
typedef unsigned int   u32;
typedef unsigned long long u64;

__device__ __forceinline__ float sigm(float x) { return 1.0f / (1.0f + __expf(-x)); }

__device__ __forceinline__ u16 f2bf_rn(float x) {
    u32 u = __float_as_uint(x);
    u += 0x7FFFu + ((u >> 16) & 1u);
    return (u16)(u >> 16);
}
__device__ __forceinline__ float bf2f(u16 h) { return __uint_as_float(((u32)h) << 16); }

// ======================= K1: prep (gather + chain + D-prep) ================
// 1024 blocks x 256 thr, 16 rows/block. Condi sigmoids staged in LDS
// (pitch 127 float4 -> chain reads are 2-way bank conflicts = free).
// Wave w gathers rows w*4..w*4+3; after barrier, wave0 lanes 0-15 run the
// 16 serial chains from LDS and store masked bf16 mastery hi/lo pairs.
__global__ __launch_bounds__(256, 4) void prep2(
    const int*   __restrict__ user_ids,
    const int*   __restrict__ item_ids,
    const float* __restrict__ item_know,
    const float* __restrict__ priori,
    const float* __restrict__ condi_p,
    const float* __restrict__ condi_n,
    const float* __restrict__ item_diff_w,
    const float* __restrict__ Wu,
    const float* __restrict__ Wi,
    u16*         __restrict__ wsp,
    u32*         __restrict__ mhi32,    // [BATCH][64] u32 = bf16 pairs, masked
    u32*         __restrict__ mlo32,
    u16*         __restrict__ dhi,      // [BATCH][128] bf16
    u16*         __restrict__ dlo)
{
    __shared__ float4 sP[16][127];      // [r][slot]; slot0=header, 1..126=steps
    __shared__ uint4  sMask[16];

    const int tid = threadIdx.x;
    const int wid = tid >> 6, j = tid & 63;
    const int r0  = blockIdx.x * 16;

    #pragma unroll 2
    for (int q = 0; q < 4; ++q) {
        const int r = wid * 4 + q, row = r0 + r;
        const int uid = user_ids[row], iid = item_ids[row];
        const float* cp = condi_p + (size_t)uid * NEDGE;
        const float* cn = condi_n + (size_t)uid * NEDGE;
        const float* kw = item_know   + (size_t)row * NKNOW;
        const float* dw = item_diff_w + (size_t)iid * NKNOW;

        // independent loads issued up front
        float a0p = cp[127 + j], a0n = cn[127 + j], b0p = cp[1 + j], b0n = cn[1 + j];
        float a1p = 0.f, a1n = 0.f, b1p = 0.f, b1n = 0.f;
        if (j < 62) { a1p = cp[191 + j]; a1n = cn[191 + j]; b1p = cp[65 + j]; b1n = cn[65 + j]; }
        float k0 = kw[j], k1 = kw[64 + j];
        float d0 = dw[j], d1 = dw[64 + j];

        float4 sA;
        sA.x = sqrtf(sigm(a0p)); sA.y = sqrtf(sigm(a0n));
        sA.z = sqrtf(sigm(b0p)); sA.w = sqrtf(sigm(b0n));
        sP[r][1 + j] = sA;
        if (j < 62) {
            float4 sB;
            sB.x = sqrtf(sigm(a1p)); sB.y = sqrtf(sigm(a1n));
            sB.z = sqrtf(sigm(b1p)); sB.w = sqrtf(sigm(b1n));
            sP[r][65 + j] = sB;
        }

        float dv0 = sigm(d0) * k0, dv1 = sigm(d1) * k1;   // know in {0,1} -> exact
        u16 h0 = f2bf_rn(dv0), h1 = f2bf_rn(dv1);
        dhi[(size_t)row * NKNOW + j]      = h0;
        dhi[(size_t)row * NKNOW + 64 + j] = h1;
        dlo[(size_t)row * NKNOW + j]      = f2bf_rn(dv0 - bf2f(h0));
        dlo[(size_t)row * NKNOW + 64 + j] = f2bf_rn(dv1 - bf2f(h1));

        u64 m0 = __ballot(k0 > 0.5f);
        u64 m1 = __ballot(k1 > 0.5f);
        if (j == 0) {
            float4 hd;
            hd.x = sigm(cp[0]); hd.y = sigm(cn[0]);
            hd.z = sigm(priori[(size_t)uid * NKNOW]); hd.w = 0.f;
            sP[r][0] = hd;
            uint4 mm; mm.x = (u32)m0; mm.y = (u32)(m0 >> 32);
            mm.z = (u32)m1; mm.w = (u32)(m1 >> 32);
            sMask[r] = mm;
        }
    }

    // merged conv_w: blocks 0..255 convert Wu/Wi fp32 -> bf16 hi/lo in wsp
    if (blockIdx.x < 256) {
        int i = blockIdx.x * 256 + tid;                  // 0..65535
        bool isU = i < 32768;
        int  jj  = isU ? i : i - 32768;
        float w  = isU ? Wu[jj] : Wi[jj];
        u16 h = f2bf_rn(w);
        u16 l = f2bf_rn(w - bf2f(h));
        int base = isU ? 0 : 65536;
        wsp[base + jj]         = h;
        wsp[base + 32768 + jj] = l;
    }
    __syncthreads();

    // ---------------- 16 serial chains (wave0 lanes 0-15) -----------------
    if (tid < 16) {
        const int r = tid, row = r0 + r;
        uint4 mm = sMask[r];
        const u64 b0 = (u64)mm.x | ((u64)mm.y << 32);
        const u64 b1 = (u64)mm.z | ((u64)mm.w << 32);
        u32* mh = mhi32 + (size_t)row * 64;
        u32* ml = mlo32 + (size_t)row * 64;

        float4 h = sP[r][0];
        float p0 = h.z;
        float p1 = fmaf(p0, h.x - h.y, h.y);
        {
            float v0 = (b0 & 1ull) ? p0 : 0.f;
            float v1 = (b0 & 2ull) ? p1 : 0.f;
            u16 q0 = f2bf_rn(v0), q1 = f2bf_rn(v1);
            mh[0] = (u32)q0 | ((u32)q1 << 16);
            ml[0] = (u32)f2bf_rn(v0 - bf2f(q0)) | ((u32)f2bf_rn(v1 - bf2f(q1)) << 16);
        }

        float pm2 = p0, pm1 = p1, pendm = 0.f;
        float4 A[7], Bv[7];

#define LOADB(buf, bi_)                                               \
    _Pragma("unroll")                                                 \
    for (int t = 0; t < 7; ++t) buf[t] = sP[r][1 + 7 * (bi_) + t];

#define STEPS(buf, bi_)                                               \
    _Pragma("unroll")                                                 \
    for (int t = 0; t < 7; ++t) {                                     \
        const int k = 2 + 7 * (bi_) + t;                              \
        float4 s = buf[t];                                            \
        float ta = fmaf(pm2, s.x - s.y, s.y);                         \
        float tb = fmaf(pm1, s.z - s.w, s.w);                         \
        float pk = ta * tb;                                           \
        bool bit = (k < 64) ? ((b0 >> k) & 1ull) : ((b1 >> (k - 64)) & 1ull); \
        float pkm = bit ? pk : 0.f;                                   \
        if (k & 1) {                                                  \
            u16 q0 = f2bf_rn(pendm), q1 = f2bf_rn(pkm);               \
            mh[k >> 1] = (u32)q0 | ((u32)q1 << 16);                   \
            ml[k >> 1] = (u32)f2bf_rn(pendm - bf2f(q0)) |             \
                         ((u32)f2bf_rn(pkm - bf2f(q1)) << 16);        \
        } else pendm = pkm;                                           \
        pm2 = pm1; pm1 = pk;                                          \
    }
        LOADB(A, 0);
        LOADB(Bv, 1);  STEPS(A, 0);
        LOADB(A, 2);   STEPS(Bv, 1);
        LOADB(Bv, 3);  STEPS(A, 2);
        LOADB(A, 4);   STEPS(Bv, 3);
        LOADB(Bv, 5);  STEPS(A, 4);
        LOADB(A, 6);   STEPS(Bv, 5);
        LOADB(Bv, 7);  STEPS(A, 6);
        LOADB(A, 8);   STEPS(Bv, 7);
        LOADB(Bv, 9);  STEPS(A, 8);
        LOADB(A, 10);  STEPS(Bv, 9);
        LOADB(Bv, 11); STEPS(A, 10);
        LOADB(A, 12);  STEPS(Bv, 11);
        LOADB(Bv, 13); STEPS(A, 12);
        LOADB(A, 14);  STEPS(Bv, 13);
        LOADB(Bv, 15); STEPS(A, 14);
        LOADB(A, 16);  STEPS(Bv, 15);
        LOADB(Bv, 17); STEPS(A, 16);
        STEPS(Bv, 17);
#undef LOADB
#undef STEPS
    }
}

// ======================= K2: gemm (R5-proven, verbatim) ====================
__global__ __launch_bounds__(256, 2) void gemm_ncd(
    const int*   __restrict__ item_ids,
    const float* __restrict__ item_disc_w,
    const float* __restrict__ bu,
    const float* __restrict__ bi,
    const u16*   __restrict__ wsp,
    const u32*   __restrict__ mhi32,
    const u32*   __restrict__ mlo32,
    const u32*   __restrict__ dhi32,
    const u32*   __restrict__ dlo32,
    float*       __restrict__ out)
{
    __shared__ float sRed[4][32];

    const int tid  = threadIdx.x;
    const int lane = tid & 63;
    const int wid  = tid >> 6;
    const int l15  = lane & 15, lq = lane >> 4;
    const int r0   = blockIdx.x * 32;

    const u16* WuH = wsp;
    const u16* WuL = wsp + 32768;
    const u16* WiH = wsp + 65536;
    const u16* WiL = wsp + 98304;

    float rowsum[2][4] = {{0.f,0.f,0.f,0.f},{0.f,0.f,0.f,0.f}};

    #pragma unroll 1
    for (int t = 0; t < 4; ++t) {
        const int hcol = wid * 64 + t * 16 + l15;
        s16x8 uh[4], ul[4], ih[4], il[4];
        #pragma unroll
        for (int kc = 0; kc < 4; ++kc) {
            const int ke = kc * 32 + lq * 8;
            uh[kc] = *(const s16x8*)(WuH + hcol * NKNOW + ke);
            ul[kc] = *(const s16x8*)(WuL + hcol * NKNOW + ke);
            ih[kc] = *(const s16x8*)(WiH + hcol * NKNOW + ke);
            il[kc] = *(const s16x8*)(WiL + hcol * NKNOW + ke);
        }
        const float bub = bu[hcol], bib = bi[hcol];

        #pragma unroll
        for (int rg = 0; rg < 2; ++rg) {
            const int row = r0 + rg * 16 + l15;
            f32x4 accU = {0.f, 0.f, 0.f, 0.f};
            f32x4 accV = {0.f, 0.f, 0.f, 0.f};
            #pragma unroll
            for (int kc = 0; kc < 4; ++kc) {
                const int aoff = row * 64 + kc * 16 + lq * 4;
                s16x8 mh = *(const s16x8*)(mhi32 + aoff);
                s16x8 mlv = *(const s16x8*)(mlo32 + aoff);
                s16x8 dh = *(const s16x8*)(dhi32 + aoff);
                s16x8 dl = *(const s16x8*)(dlo32 + aoff);
                accU = __builtin_amdgcn_mfma_f32_16x16x32_bf16(mh, uh[kc], accU, 0, 0, 0);
                accU = __builtin_amdgcn_mfma_f32_16x16x32_bf16(mh, ul[kc], accU, 0, 0, 0);
                accU = __builtin_amdgcn_mfma_f32_16x16x32_bf16(mlv, uh[kc], accU, 0, 0, 0);
                accV = __builtin_amdgcn_mfma_f32_16x16x32_bf16(dh, ih[kc], accV, 0, 0, 0);
                accV = __builtin_amdgcn_mfma_f32_16x16x32_bf16(dh, il[kc], accV, 0, 0, 0);
                accV = __builtin_amdgcn_mfma_f32_16x16x32_bf16(dl, ih[kc], accV, 0, 0, 0);
            }
            #pragma unroll
            for (int j = 0; j < 4; ++j) {
                float x = accU[j] + bub;
                float u = 1.0f - 2.0f / (1.0f + __expf(2.0f * x));   // tanh
                float v = sigm(accV[j] + bib);
                rowsum[rg][j] += u * v;
            }
        }
    }

    #pragma unroll
    for (int rg = 0; rg < 2; ++rg)
        #pragma unroll
        for (int j = 0; j < 4; ++j) {
            float v = rowsum[rg][j];
            v += __shfl_xor(v, 1);
            v += __shfl_xor(v, 2);
            v += __shfl_xor(v, 4);
            v += __shfl_xor(v, 8);
            if (l15 == 0) sRed[wid][rg * 16 + lq * 4 + j] = v;
        }
    __syncthreads();

    if (tid < 32) {
        const int row = r0 + tid;
        float s = sRed[0][tid] + sRed[1][tid] + sRed[2][tid] + sRed[3][tid];
        float disc = sigm(item_disc_w[item_ids[row]]);
        out[row] = sigm(s - disc);
    }
}

// ======================= Fallback: R1 fused kernel (proven) ================
__device__ __forceinline__ int swz(int row, int kbyte) {
    return row * 256 + (kbyte ^ ((row & 7) << 4));
}
__device__ __forceinline__ void store_pair(char* Mh, char* Ml, int r, int k0, float va, float vb) {
    int off = swz(r, k0 * 2);
    u16 ha = f2bf_rn(va); u16 la = f2bf_rn(va - bf2f(ha));
    u16 hb = f2bf_rn(vb); u16 lb = f2bf_rn(vb - bf2f(hb));
    *(u32*)(Mh + off) = (u32)ha | ((u32)hb << 16);
    *(u32*)(Ml + off) = (u32)la | ((u32)lb << 16);
}

__global__ void conv_w(const float* __restrict__ Wu, const float* __restrict__ Wi,
                       u16* __restrict__ wsp) {
    int i = blockIdx.x * 256 + threadIdx.x;
    bool isU = i < 32768;
    int  j   = isU ? i : i - 32768;
    float w  = isU ? Wu[j] : Wi[j];
    u16 h = f2bf_rn(w);
    u16 l = f2bf_rn(w - bf2f(h));
    int base = isU ? 0 : 65536;
    wsp[base + j]         = h;
    wsp[base + 32768 + j] = l;
}

__global__ __launch_bounds__(256, 3) void fused_ncd(
    const int*   __restrict__ user_ids,
    const int*   __restrict__ item_ids,
    const float* __restrict__ item_know,
    const float* __restrict__ priori,
    const float* __restrict__ condi_p,
    const float* __restrict__ condi_n,
    const float* __restrict__ item_diff_w,
    const float* __restrict__ item_disc_w,
    const float* __restrict__ bu,
    const float* __restrict__ bi,
    const u16* __restrict__ wsp,
    float*       __restrict__ out)
{
    __shared__ float sPair[RPB][508];
    __shared__ __align__(16) u16 sMhi[RPB * 128];
    __shared__ __align__(16) u16 sMlo[RPB * 128];
    __shared__ __align__(16) u16 sDhi[RPB * 128];
    __shared__ __align__(16) u16 sDlo[RPB * 128];
    __shared__ __align__(16) u16 sKmF[RPB * 128];
    __shared__ float sRed[4][RPB];
    __shared__ float sDisc[RPB];

    const int tid  = threadIdx.x;
    const int lane = tid & 63;
    const int wid  = tid >> 6;
    const int r0   = blockIdx.x * RPB;

    for (int rr = 0; rr < 4; ++rr) {
        const int r   = wid * 4 + rr;
        const int row = r0 + r;
        const int uid = user_ids[row];
        const int iid = item_ids[row];
        const float* cp = condi_p + (size_t)uid * NEDGE;
        const float* cn = condi_n + (size_t)uid * NEDGE;
        for (int e = lane; e < NEDGE; e += 64) {
            float p = sigm(cp[e]);
            float n = sigm(cn[e]);
            if (e >= 1) { p = sqrtf(p); n = sqrtf(n); }
            *(float2*)&sPair[r][2 * e] = make_float2(p, n);
        }
        const float* dw = item_diff_w + (size_t)iid * NKNOW;
        const float* kw = item_know   + (size_t)row * NKNOW;
        for (int e = lane; e < NKNOW; e += 64) {
            float kv = kw[e];
            float dv = sigm(dw[e]) * kv;
            u16 dh = f2bf_rn(dv);
            u16 dl = f2bf_rn(dv - bf2f(dh));
            int off = swz(r, 2 * e);
            *(u16*)((char*)sDhi + off) = dh;
            *(u16*)((char*)sDlo + off) = dl;
            *(u16*)((char*)sKmF + off) = (kv > 0.5f) ? (u16)0xFFFFu : (u16)0;
        }
    }
    __syncthreads();

    if (tid < RPB) {
        const int r   = tid;
        const int row = r0 + r;
        const int uid = user_ids[row];
        const int iid = item_ids[row];
        const float* P = &sPair[r][0];
        float p0 = sigm(priori[(size_t)uid * NKNOW]);
        float2 c0 = *(const float2*)&P[0];
        float p1 = c0.x * p0 + c0.y * (1.0f - p0);
        store_pair((char*)sMhi, (char*)sMlo, r, 0, p0, p1);
        float pm2 = p0, pm1 = p1, pev = 0.0f;
        for (int k = 2; k < NKNOW; ++k) {
            float2 a = *(const float2*)&P[2 * (125 + k)];
            float2 b = *(const float2*)&P[2 * (k - 1)];
            float ta = fmaf(pm2, a.x - a.y, a.y);
            float tb = fmaf(pm1, b.x - b.y, b.y);
            float pk = ta * tb;
            if (k & 1) store_pair((char*)sMhi, (char*)sMlo, r, k - 1, pev, pk);
            else       pev = pk;
            pm2 = pm1; pm1 = pk;
        }
        sDisc[r] = sigm(item_disc_w[iid]);
    }
    __syncthreads();

    const int l15 = lane & 15, lq = lane >> 4;
    const u16* WuH = wsp;
    const u16* WuL = wsp + 32768;
    const u16* WiH = wsp + 65536;
    const u16* WiL = wsp + 98304;

    float rowsum[4] = {0.f, 0.f, 0.f, 0.f};

    for (int t = 0; t < 4; ++t) {
        const int hcol = wid * 64 + t * 16 + l15;
        f32x4 accU = {0.f, 0.f, 0.f, 0.f};
        f32x4 accV = {0.f, 0.f, 0.f, 0.f};
        const u16* wuh = WuH + hcol * NKNOW;
        const u16* wul = WuL + hcol * NKNOW;
        const u16* wih = WiH + hcol * NKNOW;
        const u16* wil = WiL + hcol * NKNOW;
        #pragma unroll
        for (int kc = 0; kc < 4; ++kc) {
            const int offA = swz(l15, kc * 64 + lq * 16);
            const int ke   = kc * 32 + lq * 8;
            i32x4 km = *(const i32x4*)((const char*)sKmF + offA);
            i32x4 mh = *(const i32x4*)((const char*)sMhi + offA) & km;
            i32x4 ml = *(const i32x4*)((const char*)sMlo + offA) & km;
            s16x8 ah = *(s16x8*)&mh;
            s16x8 al = *(s16x8*)&ml;
            s16x8 bh = *(const s16x8*)((const char*)sDhi + offA);
            s16x8 bl = *(const s16x8*)((const char*)sDlo + offA);
            s16x8 uh = *(const s16x8*)(wuh + ke);
            s16x8 ul = *(const s16x8*)(wul + ke);
            s16x8 ih = *(const s16x8*)(wih + ke);
            s16x8 il = *(const s16x8*)(wil + ke);
            accU = __builtin_amdgcn_mfma_f32_16x16x32_bf16(ah, uh, accU, 0, 0, 0);
            accU = __builtin_amdgcn_mfma_f32_16x16x32_bf16(ah, ul, accU, 0, 0, 0);
            accU = __builtin_amdgcn_mfma_f32_16x16x32_bf16(al, uh, accU, 0, 0, 0);
            accV = __builtin_amdgcn_mfma_f32_16x16x32_bf16(bh, ih, accV, 0, 0, 0);
            accV = __builtin_amdgcn_mfma_f32_16x16x32_bf16(bh, il, accV, 0, 0, 0);
            accV = __builtin_amdgcn_mfma_f32_16x16x32_bf16(bl, ih, accV, 0, 0, 0);
        }
        const float bub = bu[hcol], bib = bi[hcol];
        #pragma unroll
        for (int j = 0; j < 4; ++j) {
            float x = accU[j] + bub;
            float u = 1.0f - 2.0f / (1.0f + __expf(2.0f * x));
            float v = sigm(accV[j] + bib);
            rowsum[j] += u * v;
        }
    }

    #pragma unroll
    for (int j = 0; j < 4; ++j) {
        float v = rowsum[j];
        v += __shfl_xor(v, 1);
        v += __shfl_xor(v, 2);
        v += __shfl_xor(v, 4);
        v += __shfl_xor(v, 8);
        if (l15 == 0) sRed[wid][lq * 4 + j] = v;
    }
    __syncthreads();

    if (tid < RPB) {
        float logit = sRed[0][tid] + sRed[1][tid] + sRed[2][tid] + sRed[3][tid] - sDisc[tid];
        out[r0 + tid] = sigm(logit);
    }
}

extern "C" void kernel_launch(void* const* d_in, const int* in_sizes, int n_in,
                              void* d_out, int out_size, void* d_ws, size_t ws_size,
                              hipStream_t stream) {
    const int*   user_ids    = (const int*)  d_in[0];
    const int*   item_ids    = (const int*)  d_in[1];
    const float* item_know   = (const float*)d_in[2];
    const float* priori      = (const float*)d_in[3];
    const float* condi_p     = (const float*)d_in[4];
    const float* condi_n     = (const float*)d_in[5];
    const float* item_diff_w = (const float*)d_in[6];
    const float* item_disc_w = (const float*)d_in[7];
    const float* Wu          = (const float*)d_in[8];
    const float* bu          = (const float*)d_in[9];
    const float* Wi          = (const float*)d_in[10];
    const float* bi          = (const float*)d_in[11];
    float* out = (float*)d_out;

    char* base = (char*)d_ws;
    u16* wsp   = (u16*)base;                                   // 256 KiB
    u32* mhi32 = (u32*)(base + 0x0040000);                     // 4 MiB
    u32* mlo32 = (u32*)(base + 0x0440000);                     // 4 MiB
    u16* dhi   = (u16*)(base + 0x0840000);                     // 4 MiB
    u16* dlo   = (u16*)(base + 0x0C40000);                     // 4 MiB
    const size_t need = 0x1040000;                             // ~16.25 MiB

    if (ws_size >= need) {
        prep2<<<BATCH / 16, 256, 0, stream>>>(
            user_ids, item_ids, item_know, priori, condi_p, condi_n,
            item_diff_w, Wu, Wi, wsp, mhi32, mlo32, dhi, dlo);
        gemm_ncd<<<BATCH / 32, 256, 0, stream>>>(
            item_ids, item_disc_w, bu, bi, wsp,
            mhi32, mlo32, (const u32*)dhi, (const u32*)dlo, out);
    } else {
        conv_w<<<256, 256, 0, stream>>>(Wu, Wi, wsp);
        fused_ncd<<<BATCH / RPB, 256, 0, stream>>>(
            user_ids, item_ids, item_know, priori, condi_p, condi_n,
            item_diff_w, item_disc_w, bu, bi, wsp, out);
    }
}